// Round 10
// baseline (45.061 us; speedup 1.0000x reference)
//
#include <hip/hip_runtime.h>

#define H     128
#define W     128
#define HO    126
#define WO    126
#define NPIX  (HO * WO)          // 15876

// 4-pixel group math on rows r0,r1,r2 (cols x0..x0+5)
__device__ __forceinline__ float grp(const float r0[6], const float r1[6],
                                     const float r2[6], bool full) {
    float cs[6], cq[6], cm[6];
#pragma unroll
    for (int c = 0; c < 6; ++c) {
        cs[c] = r0[c] + r1[c] + r2[c];
        cq[c] = fmaf(r0[c], r0[c], fmaf(r1[c], r1[c], r2[c] * r2[c]));
        cm[c] = fmaxf(r0[c], fmaxf(r1[c], r2[c]));   // -> v_max3
    }

    float bnv[4];
#pragma unroll
    for (int k = 0; k < 4; ++k) {
        const float ctr  = r1[k + 1];
        const float sum  = cs[k] + cs[k + 1] + cs[k + 2];
        const float ss   = cq[k] + cq[k + 1] + cq[k + 2];
        const float wmax = fmaxf(cm[k], fmaxf(cm[k + 1], cm[k + 2]));

        float d[8];
        d[0] = r0[k]     - ctr;  d[1] = r0[k + 1] - ctr;
        d[2] = r0[k + 2] - ctr;  d[3] = r1[k]     - ctr;
        d[4] = r1[k + 2] - ctr;  d[5] = r2[k]     - ctr;
        d[6] = r2[k + 1] - ctr;  d[7] = r2[k + 2] - ctr;

        const float sad = ((fabsf(d[0]) + fabsf(d[1])) + (fabsf(d[2]) + fabsf(d[3])))
                        + ((fabsf(d[4]) + fabsf(d[5])) + (fabsf(d[6]) + fabsf(d[7])));
        const float thr = sad * (1.f / 9.f);

        int b0 = (sad <= 0.f) ? 1 : 0;   // center tap: 0 >= thr
        b0 += d[0] >= thr;
        b0 += d[1] >= thr;
        b0 += d[2] >= thr;
        b0 += d[3] >= thr;
        int b1 = d[4] >= thr;
        b1 += d[5] >= thr;
        b1 += d[6] >= thr;
        b1 += d[7] >= thr;
        const float bv = (float)(b0 + b1);

        const float var9 = fmaf(sum, -sum, 9.f * ss);                // 81*var
        const float sd9  = __builtin_amdgcn_sqrtf(fmaxf(var9, 0.f)); // 9*std
        const float nf   = fmaf(sum, -1.f / 2295.f, bv * (1.f / 255.f));
        bnv[k] = fmaf(nf, fmaf(sd9, 1.f / 9.f, -wmax), wmax);
    }

    float gs = bnv[0] + bnv[1];
    gs += full ? (bnv[2] + bnv[3]) : 0.f;   // strip 31: px 2,3 out of range
    return gs;
}

// One block = one plane. 448 threads = 32 x-strips x 14 nine-row chunks.
// No LDS staging: each thread slides a 3-row x 6-col register window down
// 9 output rows, loading one row per step straight from global (L1-resident).
__global__ __launch_bounds__(448) void bp_kernel(const float* __restrict__ x,
                                                 float* __restrict__ out) {
    __shared__ float wred[7];

    const int t     = threadIdx.x;
    const int s     = t & 31;        // x-strip: out px 4s..4s+3
    const int c     = t >> 5;        // 9-row chunk: out rows 9c..9c+8
    const int plane = blockIdx.x;

    const bool full = (s != 31);
    const float* p  = x + (size_t)plane * (H * W) + (size_t)(9 * c) * W + 4 * s;
    const int off2  = full ? 4 : 2;  // !full: reload cols 2,3 (valid addr, masked px)

    float r[3][6];
    float acc = 0.f;

    // helper to load row i of the chunk into slot
#define LDROW(slot, i)                                              \
    {                                                               \
        const float4 a_ = *(const float4*)(p + (i) * W);            \
        const float2 b_ = *(const float2*)(p + (i) * W + off2);     \
        r[slot][0] = a_.x; r[slot][1] = a_.y;                       \
        r[slot][2] = a_.z; r[slot][3] = a_.w;                       \
        r[slot][4] = b_.x; r[slot][5] = b_.y;                       \
    }

    LDROW(0, 0)
    LDROW(1, 1)
#pragma unroll
    for (int i = 0; i < 9; ++i) {
        LDROW((i + 2) % 3, i + 2)
        acc += grp(r[i % 3], r[(i + 1) % 3], r[(i + 2) % 3], full);
    }
#undef LDROW

    // ---- block reduction: 7 waves ----
#pragma unroll
    for (int off = 32; off > 0; off >>= 1)
        acc += __shfl_down(acc, off, 64);
    if ((t & 63) == 0) wred[t >> 6] = acc;
    __syncthreads();
    if (t < 64) {
        float v = (t < 7) ? wred[t] : 0.f;
        v += __shfl_down(v, 4, 64);
        v += __shfl_down(v, 2, 64);
        v += __shfl_down(v, 1, 64);
        if (t == 0) out[plane] = v * (1.f / NPIX);
    }
}

extern "C" void kernel_launch(void* const* d_in, const int* in_sizes, int n_in,
                              void* d_out, int out_size, void* d_ws, size_t ws_size,
                              hipStream_t stream) {
    const float* x = (const float*)d_in[0];
    float* out = (float*)d_out;
    bp_kernel<<<dim3(16 * 64), dim3(448), 0, stream>>>(x, out);
}